// Round 3
// baseline (307.740 us; speedup 1.0000x reference)
//
#include <hip/hip_runtime.h>
#include <math.h>

// Problem constants: B=32, H=1024, W=1024, N=100000
#define RD_H 1024
#define RD_W 1024
#define RD_N 100000
#define RD_B 32
#define BDIM 256
#define NXCD 8
#define IMGS_PER_XCD 4                 // 32 images / 8 XCDs
#define IMG_PIX (RD_H * RD_W)          // 4 MB per image

// Binning geometry
#define NBANDS 64                      // bands per image
#define BAND_ROWS 16                   // 1024 / 64 rows per band
#define BAND_CAP 3584                  // mean 3125 + 8.3 sigma -> overflow P ~ 1e-16
#define P0_UNROLL 8
#define P0_PTS (BDIM * P0_UNROLL)      // 2048 points per bin block
#define P0_CHUNKS 49                   // ceil(100000 / 2048); tail chunk = 1696 (div by 8)

// Workspace layout (bytes)
#define WS_COUNTERS_OFF 0u
#define WS_COUNTERS_SZ  (RD_B * NBANDS * 4)                       // 8 KB
#define WS_RECORDS_OFF  8192u
#define WS_RECORDS_SZ   ((size_t)RD_B * NBANDS * BAND_CAP * 4)    // 29,360,128
#define WS_ZPAIR_OFF    (WS_RECORDS_OFF + WS_RECORDS_SZ)          // 29,368,320 (16-aligned)
#define WS_ZPAIR_SZ     ((size_t)RD_B * 2 * RD_N * 4)             // 25,600,000
#define WS_NEED         (WS_ZPAIR_OFF + WS_ZPAIR_SZ)              // ~52.4 MiB

typedef __attribute__((address_space(3))) void lds_void;
typedef const __attribute__((address_space(1))) void gbl_void;
typedef __attribute__((ext_vector_type(4))) int   ivec4;   // nontemporal-compatible
typedef __attribute__((ext_vector_type(4))) float fvec4;

__device__ __forceinline__ float rd_term(float za, float zb, int od) {
    float diff = za - zb;
    float gt   = (float)(od - 1);        // {-1, 0, 1}
    float mask = fabsf(gt);              // {0, 1}
    // stable softplus(-gt*diff) = max(x,0) + log1p(exp(-|x|))
    float x  = -gt * diff;
    float sp = fmaxf(x, 0.0f) + log1pf(__expf(-fabsf(x)));
    return mask * sp + (1.0f - mask) * diff * diff;
}

// ---------------------------------------------------------------------------
// Pass I: init (out + bin counters). d_out is poisoned before every launch.
__global__ void rd_init_kernel(float* out, unsigned* counters) {
    int i = blockIdx.x * blockDim.x + threadIdx.x;
    if (i == 0) out[0] = 0.0f;
    if (i < RD_B * NBANDS) counters[i] = 0;
}

// ---------------------------------------------------------------------------
// Pass II: bin endpoints by (img, band). Streaming reads; scattered
// fire-and-forget record stores (stores never stall the wave).
// record u32 = x(10) | y_off(4) | side(1) | pid(17)
__global__ __launch_bounds__(BDIM) void rd_bin_kernel(
    const int* __restrict__ xA, const int* __restrict__ yA,
    const int* __restrict__ xB, const int* __restrict__ yB,
    unsigned* __restrict__ counters,    // [32][64]
    unsigned* __restrict__ records)     // [32][64][BAND_CAP]
{
    __shared__ unsigned hist[NBANDS];   // phase1: histogram, phase2: cursor
    __shared__ unsigned basebuf[NBANDS];

    // img -> XCD pinning (img/4 == xcd), matching the gather pass, so this
    // image's record regions write-combine inside one XCD's L2.
    const int xcd   = blockIdx.x & (NXCD - 1);
    const int k     = blockIdx.x / NXCD;            // 0..195
    const int img   = xcd * IMGS_PER_XCD + k / P0_CHUNKS;
    const int chunk = k % P0_CHUNKS;

    const int tid = threadIdx.x;
    if (tid < NBANDS) hist[tid] = 0;
    __syncthreads();

    const int  n0     = chunk * P0_PTS + tid * P0_UNROLL;  // within-image point idx
    const bool activ  = (n0 < RD_N);    // tail chunk is 1696 = 212*8 -> all-8-or-none
    const long i0     = (long)img * RD_N + n0;

    int xa[P0_UNROLL], ya[P0_UNROLL], xb[P0_UNROLL], yb[P0_UNROLL];
    if (activ) {
        // coalesced ivec4 x2 per array; streams read exactly once -> nontemporal
        #pragma unroll
        for (int v = 0; v < 2; ++v) {
            ivec4 a = __builtin_nontemporal_load((const ivec4*)(xA + i0) + v);
            ivec4 b = __builtin_nontemporal_load((const ivec4*)(yA + i0) + v);
            ivec4 c = __builtin_nontemporal_load((const ivec4*)(xB + i0) + v);
            ivec4 d = __builtin_nontemporal_load((const ivec4*)(yB + i0) + v);
            #pragma unroll
            for (int e = 0; e < 4; ++e) {
                xa[4*v+e] = a[e]; ya[4*v+e] = b[e];
                xb[4*v+e] = c[e]; yb[4*v+e] = d[e];
            }
        }
        // phase 1: LDS histogram (16 DS-atomics/thread, pipelined)
        #pragma unroll
        for (int j = 0; j < P0_UNROLL; ++j) {
            atomicAdd(&hist[ya[j] >> 4], 1u);
            atomicAdd(&hist[yb[j] >> 4], 1u);
        }
    }
    __syncthreads();

    // reserve contiguous ranges in the global per-(img,band) regions
    if (tid < NBANDS) {
        unsigned h = hist[tid];
        basebuf[tid] = h ? atomicAdd(&counters[img * NBANDS + tid], h) : 0u;
        hist[tid] = 0;                   // reuse as phase-2 cursor
    }
    __syncthreads();

    if (activ) {
        unsigned* __restrict__ rimg = records + (size_t)img * NBANDS * BAND_CAP;
        #pragma unroll
        for (int j = 0; j < P0_UNROLL; ++j) {
            const unsigned pid = (unsigned)(n0 + j);
            {   // side A
                const int band = ya[j] >> 4;
                unsigned idx = basebuf[band] + atomicAdd(&hist[band], 1u);
                if (idx < BAND_CAP)
                    rimg[(size_t)band * BAND_CAP + idx] =
                        ((unsigned)xa[j] << 22) | ((unsigned)(ya[j] & 15) << 18) | pid;
            }
            {   // side B
                const int band = yb[j] >> 4;
                unsigned idx = basebuf[band] + atomicAdd(&hist[band], 1u);
                if (idx < BAND_CAP)
                    rimg[(size_t)band * BAND_CAP + idx] =
                        ((unsigned)xb[j] << 22) | ((unsigned)(yb[j] & 15) << 18) |
                        (1u << 17) | pid;
            }
        }
    }
}

// ---------------------------------------------------------------------------
// Pass III: per (img, band): stream the 64 KB depth band into LDS, then each
// record does a random LDS read (no L1/L2 involvement) and a fire-and-forget
// scattered store of z into z_pair[img][side][pid].
__global__ __launch_bounds__(BDIM) void rd_gather_kernel(
    const float* __restrict__ depth,
    const unsigned* __restrict__ counters,
    const unsigned* __restrict__ records,
    float* __restrict__ zpair)
{
    __shared__ float band_lds[BAND_ROWS * RD_W];   // 64 KB -> 2 blocks/CU

    const int xcd  = blockIdx.x & (NXCD - 1);
    const int k    = blockIdx.x / NXCD;            // 0..255
    const int img  = xcd * IMGS_PER_XCD + (k >> 6);
    const int band = k & (NBANDS - 1);

    const int tid = threadIdx.x;
    const float* src = depth + (size_t)img * IMG_PIX + (size_t)band * BAND_ROWS * RD_W;

    // stage 64 KB: 16 x (256 lanes x 16 B). LDS dest = wave-uniform base + lane*16.
    #pragma unroll
    for (int c = 0; c < 16; ++c) {
        const int f4 = c * BDIM + tid;             // float4 index 0..4095
        __builtin_amdgcn_global_load_lds(
            (gbl_void*)((const fvec4*)src + f4),
            (lds_void*)&band_lds[(c * BDIM + (tid & ~63)) * 4],
            16, 0, 0);
    }
    __syncthreads();   // waits vmcnt(0) before barrier

    const unsigned cnt = min(counters[img * NBANDS + band], (unsigned)BAND_CAP);
    const unsigned* __restrict__ recs =
        records + (size_t)(img * NBANDS + band) * BAND_CAP;
    float* __restrict__ zp = zpair + (size_t)img * 2 * RD_N;

    for (unsigned i = tid; i < cnt; i += BDIM) {
        const unsigned r = __builtin_nontemporal_load(recs + i);
        const int x    = r >> 22;
        const int yoff = (r >> 18) & 15;
        const int side = (r >> 17) & 1;
        const int pid  = r & 0x1FFFF;
        zp[side * RD_N + pid] = band_lds[yoff * RD_W + x];
    }
}

// ---------------------------------------------------------------------------
// Pass IV: streaming combine + reduce.
__global__ __launch_bounds__(BDIM) void rd_loss_from_z(
    const float* __restrict__ zpair,
    const int* __restrict__ ord,
    float* __restrict__ out, float inv_total)
{
    const int xcd   = blockIdx.x & (NXCD - 1);    // same img->XCD map: z_pair L2-hot
    const int k     = blockIdx.x / NXCD;
    const int img   = xcd * IMGS_PER_XCD + k / P0_CHUNKS;
    const int chunk = k % P0_CHUNKS;
    const int n0    = chunk * P0_PTS + threadIdx.x * P0_UNROLL;

    float loss = 0.0f;
    if (n0 < RD_N) {
        const float* za = zpair + (size_t)img * 2 * RD_N + n0;
        const float* zb = za + RD_N;
        const int*   op = ord + (long)img * RD_N + n0;
        float a[8], b[8]; int o[8];
        #pragma unroll
        for (int v = 0; v < 2; ++v) {
            fvec4 av = ((const fvec4*)za)[v];
            fvec4 bv = ((const fvec4*)zb)[v];
            ivec4 ov = __builtin_nontemporal_load((const ivec4*)op + v);
            #pragma unroll
            for (int e = 0; e < 4; ++e) {
                a[4*v+e] = av[e]; b[4*v+e] = bv[e]; o[4*v+e] = ov[e];
            }
        }
        #pragma unroll
        for (int j = 0; j < 8; ++j) loss += rd_term(a[j], b[j], o[j]);
    }

    #pragma unroll
    for (int off = 32; off > 0; off >>= 1)
        loss += __shfl_down(loss, off, 64);

    __shared__ float wsum[BDIM / 64];
    const int lane = threadIdx.x & 63;
    const int wid  = threadIdx.x >> 6;
    if (lane == 0) wsum[wid] = loss;
    __syncthreads();
    if (threadIdx.x == 0) {
        float s = 0.0f;
        #pragma unroll
        for (int w = 0; w < BDIM / 64; ++w) s += wsum[w];
        atomicAdd(out, s * inv_total);
    }
}

// ---------------------------------------------------------------------------
// Fallback (proven 265 us round-0 kernel) if workspace is too small.
#define FB_UNROLL 8
#define FB_KPB 196
__global__ void rd_zero_kernel(float* out) { out[0] = 0.0f; }
__global__ __launch_bounds__(BDIM) void rd_loss_fallback(
    const float* __restrict__ depth,
    const int* __restrict__ xA, const int* __restrict__ yA,
    const int* __restrict__ xB, const int* __restrict__ yB,
    const int* __restrict__ ord,
    float* __restrict__ out, int total, float inv_total)
{
    int v  = (blockIdx.x % NXCD) * FB_KPB + (blockIdx.x / NXCD);
    int i0 = (v * BDIM + threadIdx.x) * FB_UNROLL;
    float loss = 0.0f;
    if (i0 < total) {
        int b = i0 / RD_N;
        const float* img = depth + (long)b * IMG_PIX;
        int4 xa[2] = {((const int4*)(xA+i0))[0], ((const int4*)(xA+i0))[1]};
        int4 ya[2] = {((const int4*)(yA+i0))[0], ((const int4*)(yA+i0))[1]};
        int4 xb[2] = {((const int4*)(xB+i0))[0], ((const int4*)(xB+i0))[1]};
        int4 yb[2] = {((const int4*)(yB+i0))[0], ((const int4*)(yB+i0))[1]};
        int4 od[2] = {((const int4*)(ord+i0))[0], ((const int4*)(ord+i0))[1]};
        const int* xap = (const int*)xa; const int* yap = (const int*)ya;
        const int* xbp = (const int*)xb; const int* ybp = (const int*)yb;
        const int* odp = (const int*)od;
        float za[FB_UNROLL], zb[FB_UNROLL];
        #pragma unroll
        for (int j = 0; j < FB_UNROLL; ++j) za[j] = img[yap[j]*RD_W + xap[j]];
        #pragma unroll
        for (int j = 0; j < FB_UNROLL; ++j) zb[j] = img[ybp[j]*RD_W + xbp[j]];
        #pragma unroll
        for (int j = 0; j < FB_UNROLL; ++j) loss += rd_term(za[j], zb[j], odp[j]);
    }
    #pragma unroll
    for (int off = 32; off > 0; off >>= 1) loss += __shfl_down(loss, off, 64);
    __shared__ float wsum[BDIM / 64];
    int lane = threadIdx.x & 63, wid = threadIdx.x >> 6;
    if (lane == 0) wsum[wid] = loss;
    __syncthreads();
    if (threadIdx.x == 0) {
        float s = 0.0f;
        #pragma unroll
        for (int w = 0; w < BDIM / 64; ++w) s += wsum[w];
        atomicAdd(out, s * inv_total);
    }
}

// ---------------------------------------------------------------------------
extern "C" void kernel_launch(void* const* d_in, const int* in_sizes, int n_in,
                              void* d_out, int out_size, void* d_ws, size_t ws_size,
                              hipStream_t stream) {
    const float* depth = (const float*)d_in[0];
    const int*   xA    = (const int*)d_in[1];
    const int*   yA    = (const int*)d_in[2];
    const int*   xB    = (const int*)d_in[3];
    const int*   yB    = (const int*)d_in[4];
    const int*   ord   = (const int*)d_in[5];
    float* out = (float*)d_out;

    const int total = in_sizes[1];               // B*N = 3,200,000
    const float inv_total = 1.0f / (float)total;

    if (ws_size < WS_NEED || total != RD_B * RD_N) {
        rd_zero_kernel<<<1, 1, 0, stream>>>(out);
        rd_loss_fallback<<<NXCD * FB_KPB, BDIM, 0, stream>>>(
            depth, xA, yA, xB, yB, ord, out, total, inv_total);
        return;
    }

    unsigned* counters = (unsigned*)((char*)d_ws + WS_COUNTERS_OFF);
    unsigned* records  = (unsigned*)((char*)d_ws + WS_RECORDS_OFF);
    float*    zpair    = (float*)((char*)d_ws + WS_ZPAIR_OFF);

    rd_init_kernel<<<(RD_B * NBANDS + BDIM - 1) / BDIM, BDIM, 0, stream>>>(out, counters);
    rd_bin_kernel<<<NXCD * IMGS_PER_XCD * P0_CHUNKS, BDIM, 0, stream>>>(   // 1568
        xA, yA, xB, yB, counters, records);
    rd_gather_kernel<<<NXCD * IMGS_PER_XCD * NBANDS, BDIM, 0, stream>>>(   // 2048
        depth, counters, records, zpair);
    rd_loss_from_z<<<NXCD * IMGS_PER_XCD * P0_CHUNKS, BDIM, 0, stream>>>(  // 1568
        zpair, ord, out, inv_total);
}

// Round 4
// 296.555 us; speedup vs baseline: 1.0377x; 1.0377x over previous
//
#include <hip/hip_runtime.h>
#include <math.h>

// Problem constants: B=32, H=1024, W=1024, N=100000
#define RD_H 1024
#define RD_W 1024
#define RD_N 100000
#define RD_B 32
#define BDIM 256
#define NXCD 8
#define IMGS_PER_XCD 4                 // 32 images / 8 XCDs
#define IMG_PIX (RD_H * RD_W)          // 4 MB per image

// Binning geometry: 128 bands x 8 rows -> 32 KB band in LDS (4 blocks/CU)
#define NBANDS 128
#define BAND_ROWS 8
#define BAND_CAP 1920                  // mean 1562.5 + 9.1 sigma -> overflow P ~ 1e-19
#define P0_UNROLL 8
#define P0_PTS (BDIM * P0_UNROLL)      // 2048 points per bin block
#define P0_CHUNKS 49                   // ceil(100000 / 2048); tail chunk = 1696 (div by 8)
#define MAX_REC (2 * P0_PTS)           // 4096 records per bin block

// Workspace layout (bytes)
#define WS_COUNTERS_OFF 0u
#define WS_COUNTERS_SZ  (RD_B * NBANDS * 4)                       // 16 KB
#define WS_RECORDS_OFF  16384u
#define WS_RECORDS_SZ   ((size_t)RD_B * NBANDS * BAND_CAP * 4)    // 31,457,280
#define WS_ZPAIR_OFF    (WS_RECORDS_OFF + WS_RECORDS_SZ)          // 31,473,664 (16-aligned)
#define WS_ZPAIR_SZ     ((size_t)RD_B * 2 * RD_N * 4)             // 25,600,000
#define WS_NEED         (WS_ZPAIR_OFF + WS_ZPAIR_SZ)              // ~54.5 MiB

typedef __attribute__((address_space(3))) void lds_void;
typedef const __attribute__((address_space(1))) void gbl_void;
typedef __attribute__((ext_vector_type(4))) int   ivec4;   // nontemporal-compatible
typedef __attribute__((ext_vector_type(4))) float fvec4;

__device__ __forceinline__ float rd_term(float za, float zb, int od) {
    float diff = za - zb;
    float gt   = (float)(od - 1);        // {-1, 0, 1}
    float mask = fabsf(gt);              // {0, 1}
    // stable softplus(-gt*diff) = max(x,0) + log1p(exp(-|x|))
    float x  = -gt * diff;
    float sp = fmaxf(x, 0.0f) + log1pf(__expf(-fabsf(x)));
    return mask * sp + (1.0f - mask) * diff * diff;
}

// ---------------------------------------------------------------------------
// Pass I: init (out + bin counters). Everything is re-poisoned each iteration.
__global__ void rd_init_kernel(float* out, unsigned* counters) {
    int i = blockIdx.x * blockDim.x + threadIdx.x;
    if (i == 0) out[0] = 0.0f;
    if (i < RD_B * NBANDS) counters[i] = 0;
}

// ---------------------------------------------------------------------------
// Pass II: bin endpoints by (img, band) with an in-LDS counting sort, then
// drain to global in band-contiguous COALESCED runs (the round-3 version's
// 6.4M scattered 4B stores were ~16x more line transactions than needed).
// record u32 = x(10)<<21 | y_off(3)<<18 | side(1)<<17 | pid(17)
__global__ __launch_bounds__(BDIM) void rd_bin_kernel(
    const int* __restrict__ xA, const int* __restrict__ yA,
    const int* __restrict__ xB, const int* __restrict__ yB,
    unsigned* __restrict__ counters,    // [32][128]
    unsigned* __restrict__ records)     // [32][128][BAND_CAP]
{
    __shared__ unsigned hist[NBANDS];        // phase1: counts, phase2: cursors
    __shared__ unsigned lstart[NBANDS + 1];  // local prefix (lstart[128] = total)
    __shared__ unsigned basebuf[NBANDS];     // global base per band
    __shared__ unsigned srec[MAX_REC];       // 16 KB sorted records
    __shared__ unsigned char sband[MAX_REC]; // 4 KB band id per slot

    // img -> XCD pinning (img/4 == xcd): records stay dirty in that XCD's L2
    // until the gather pass (same pinning) reads them back.
    const int xcd   = blockIdx.x & (NXCD - 1);
    const int k     = blockIdx.x / NXCD;            // 0..195
    const int img   = xcd * IMGS_PER_XCD + k / P0_CHUNKS;
    const int chunk = k % P0_CHUNKS;

    const int tid = threadIdx.x;
    if (tid < NBANDS) hist[tid] = 0;
    __syncthreads();

    const int  n0     = chunk * P0_PTS + tid * P0_UNROLL;  // within-image point idx
    const bool activ  = (n0 < RD_N);    // tail chunk is 1696 = 212*8 -> all-8-or-none
    const long i0     = (long)img * RD_N + n0;

    int xa[P0_UNROLL], ya[P0_UNROLL], xb[P0_UNROLL], yb[P0_UNROLL];
    if (activ) {
        // coalesced ivec4 x2 per array; streams read exactly once -> nontemporal
        #pragma unroll
        for (int v = 0; v < 2; ++v) {
            ivec4 a = __builtin_nontemporal_load((const ivec4*)(xA + i0) + v);
            ivec4 b = __builtin_nontemporal_load((const ivec4*)(yA + i0) + v);
            ivec4 c = __builtin_nontemporal_load((const ivec4*)(xB + i0) + v);
            ivec4 d = __builtin_nontemporal_load((const ivec4*)(yB + i0) + v);
            #pragma unroll
            for (int e = 0; e < 4; ++e) {
                xa[4*v+e] = a[e]; ya[4*v+e] = b[e];
                xb[4*v+e] = c[e]; yb[4*v+e] = d[e];
            }
        }
        // phase 1: LDS histogram
        #pragma unroll
        for (int j = 0; j < P0_UNROLL; ++j) {
            atomicAdd(&hist[ya[j] >> 3], 1u);
            atomicAdd(&hist[yb[j] >> 3], 1u);
        }
    }
    __syncthreads();

    // reserve global ranges + local prefix (both only READ hist here)
    if (tid < NBANDS) {
        unsigned h = hist[tid];
        basebuf[tid] = h ? atomicAdd(&counters[img * NBANDS + tid], h) : 0u;
    }
    if (tid == 0) {
        unsigned run = 0;
        for (int b = 0; b < NBANDS; ++b) { lstart[b] = run; run += hist[b]; }
        lstart[NBANDS] = run;
    }
    __syncthreads();
    if (tid < NBANDS) hist[tid] = 0;     // reuse as phase-2 cursor
    __syncthreads();

    // phase 2: counting-sort scatter INTO LDS (line-free, bank-level cost)
    if (activ) {
        #pragma unroll
        for (int j = 0; j < P0_UNROLL; ++j) {
            const unsigned pid = (unsigned)(n0 + j);
            {   // side A
                const int band = ya[j] >> 3;
                unsigned slot = lstart[band] + atomicAdd(&hist[band], 1u);
                srec[slot]  = ((unsigned)xa[j] << 21) |
                              ((unsigned)(ya[j] & 7) << 18) | pid;
                sband[slot] = (unsigned char)band;
            }
            {   // side B
                const int band = yb[j] >> 3;
                unsigned slot = lstart[band] + atomicAdd(&hist[band], 1u);
                srec[slot]  = ((unsigned)xb[j] << 21) |
                              ((unsigned)(yb[j] & 7) << 18) |
                              (1u << 17) | pid;
                sband[slot] = (unsigned char)band;
            }
        }
    }
    __syncthreads();

    // phase 3: coalesced drain — consecutive slots are band-contiguous, so
    // consecutive lanes store to consecutive global addresses (runs ~128 B).
    const unsigned nrec = lstart[NBANDS];
    unsigned* __restrict__ rimg = records + (size_t)img * NBANDS * BAND_CAP;
    for (unsigned s = tid; s < nrec; s += BDIM) {
        const unsigned b   = sband[s];
        const unsigned idx = basebuf[b] + (s - lstart[b]);
        if (idx < BAND_CAP)
            rimg[(size_t)b * BAND_CAP + idx] = srec[s];
    }
}

// ---------------------------------------------------------------------------
// Pass III: per (img, band): stream the 32 KB depth band into LDS, then each
// record does a random LDS read and a fire-and-forget scattered store of z
// into z_pair[img][side][pid] (L2-resident per XCD: 3.2 MB < 4 MB).
__global__ __launch_bounds__(BDIM) void rd_gather_kernel(
    const float* __restrict__ depth,
    const unsigned* __restrict__ counters,
    const unsigned* __restrict__ records,
    float* __restrict__ zpair)
{
    __shared__ float band_lds[BAND_ROWS * RD_W];   // 32 KB -> 4 blocks/CU

    const int xcd  = blockIdx.x & (NXCD - 1);
    const int k    = blockIdx.x / NXCD;            // 0..511
    const int img  = xcd * IMGS_PER_XCD + (k >> 7);
    const int band = k & (NBANDS - 1);

    const int tid = threadIdx.x;
    const float* src = depth + (size_t)img * IMG_PIX + (size_t)band * BAND_ROWS * RD_W;

    // stage 32 KB: 8 x (256 lanes x 16 B). LDS dest = wave-uniform base + lane*16.
    #pragma unroll
    for (int c = 0; c < 8; ++c) {
        const int f4 = c * BDIM + tid;             // float4 index 0..2047
        __builtin_amdgcn_global_load_lds(
            (gbl_void*)((const fvec4*)src + f4),
            (lds_void*)&band_lds[(c * BDIM + (tid & ~63)) * 4],
            16, 0, 0);
    }
    __syncthreads();   // waits vmcnt(0) before barrier

    const unsigned cnt = min(counters[img * NBANDS + band], (unsigned)BAND_CAP);
    const unsigned* __restrict__ recs =
        records + (size_t)(img * NBANDS + band) * BAND_CAP;
    float* __restrict__ zp = zpair + (size_t)img * 2 * RD_N;

    for (unsigned i = tid; i < cnt; i += BDIM) {
        const unsigned r = recs[i];                // L2-dirty from bin pass
        const int x    = (r >> 21) & 1023;
        const int yoff = (r >> 18) & 7;
        const int side = (r >> 17) & 1;
        const int pid  = r & 0x1FFFF;
        zp[side * RD_N + pid] = band_lds[yoff * RD_W + x];
    }
}

// ---------------------------------------------------------------------------
// Pass IV: streaming combine + reduce (zpair mostly L2-hot, same XCD).
__global__ __launch_bounds__(BDIM) void rd_loss_from_z(
    const float* __restrict__ zpair,
    const int* __restrict__ ord,
    float* __restrict__ out, float inv_total)
{
    const int xcd   = blockIdx.x & (NXCD - 1);
    const int k     = blockIdx.x / NXCD;
    const int img   = xcd * IMGS_PER_XCD + k / P0_CHUNKS;
    const int chunk = k % P0_CHUNKS;
    const int n0    = chunk * P0_PTS + threadIdx.x * P0_UNROLL;

    float loss = 0.0f;
    if (n0 < RD_N) {
        const float* za = zpair + (size_t)img * 2 * RD_N + n0;
        const float* zb = za + RD_N;
        const int*   op = ord + (long)img * RD_N + n0;
        float a[8], b[8]; int o[8];
        #pragma unroll
        for (int v = 0; v < 2; ++v) {
            fvec4 av = ((const fvec4*)za)[v];
            fvec4 bv = ((const fvec4*)zb)[v];
            ivec4 ov = __builtin_nontemporal_load((const ivec4*)op + v);
            #pragma unroll
            for (int e = 0; e < 4; ++e) {
                a[4*v+e] = av[e]; b[4*v+e] = bv[e]; o[4*v+e] = ov[e];
            }
        }
        #pragma unroll
        for (int j = 0; j < 8; ++j) loss += rd_term(a[j], b[j], o[j]);
    }

    #pragma unroll
    for (int off = 32; off > 0; off >>= 1)
        loss += __shfl_down(loss, off, 64);

    __shared__ float wsum[BDIM / 64];
    const int lane = threadIdx.x & 63;
    const int wid  = threadIdx.x >> 6;
    if (lane == 0) wsum[wid] = loss;
    __syncthreads();
    if (threadIdx.x == 0) {
        float s = 0.0f;
        #pragma unroll
        for (int w = 0; w < BDIM / 64; ++w) s += wsum[w];
        atomicAdd(out, s * inv_total);
    }
}

// ---------------------------------------------------------------------------
// Fallback (proven round-0 kernel) if workspace is too small / shape changes.
#define FB_UNROLL 8
#define FB_KPB 196
__global__ void rd_zero_kernel(float* out) { out[0] = 0.0f; }
__global__ __launch_bounds__(BDIM) void rd_loss_fallback(
    const float* __restrict__ depth,
    const int* __restrict__ xA, const int* __restrict__ yA,
    const int* __restrict__ xB, const int* __restrict__ yB,
    const int* __restrict__ ord,
    float* __restrict__ out, int total, float inv_total)
{
    int v  = (blockIdx.x % NXCD) * FB_KPB + (blockIdx.x / NXCD);
    int i0 = (v * BDIM + threadIdx.x) * FB_UNROLL;
    float loss = 0.0f;
    if (i0 < total) {
        int b = i0 / RD_N;
        const float* img = depth + (long)b * IMG_PIX;
        int4 xa[2] = {((const int4*)(xA+i0))[0], ((const int4*)(xA+i0))[1]};
        int4 ya[2] = {((const int4*)(yA+i0))[0], ((const int4*)(yA+i0))[1]};
        int4 xb[2] = {((const int4*)(xB+i0))[0], ((const int4*)(xB+i0))[1]};
        int4 yb[2] = {((const int4*)(yB+i0))[0], ((const int4*)(yB+i0))[1]};
        int4 od[2] = {((const int4*)(ord+i0))[0], ((const int4*)(ord+i0))[1]};
        const int* xap = (const int*)xa; const int* yap = (const int*)ya;
        const int* xbp = (const int*)xb; const int* ybp = (const int*)yb;
        const int* odp = (const int*)od;
        float za[FB_UNROLL], zb[FB_UNROLL];
        #pragma unroll
        for (int j = 0; j < FB_UNROLL; ++j) za[j] = img[yap[j]*RD_W + xap[j]];
        #pragma unroll
        for (int j = 0; j < FB_UNROLL; ++j) zb[j] = img[ybp[j]*RD_W + xbp[j]];
        #pragma unroll
        for (int j = 0; j < FB_UNROLL; ++j) loss += rd_term(za[j], zb[j], odp[j]);
    }
    #pragma unroll
    for (int off = 32; off > 0; off >>= 1) loss += __shfl_down(loss, off, 64);
    __shared__ float wsum[BDIM / 64];
    int lane = threadIdx.x & 63, wid = threadIdx.x >> 6;
    if (lane == 0) wsum[wid] = loss;
    __syncthreads();
    if (threadIdx.x == 0) {
        float s = 0.0f;
        #pragma unroll
        for (int w = 0; w < BDIM / 64; ++w) s += wsum[w];
        atomicAdd(out, s * inv_total);
    }
}

// ---------------------------------------------------------------------------
extern "C" void kernel_launch(void* const* d_in, const int* in_sizes, int n_in,
                              void* d_out, int out_size, void* d_ws, size_t ws_size,
                              hipStream_t stream) {
    const float* depth = (const float*)d_in[0];
    const int*   xA    = (const int*)d_in[1];
    const int*   yA    = (const int*)d_in[2];
    const int*   xB    = (const int*)d_in[3];
    const int*   yB    = (const int*)d_in[4];
    const int*   ord   = (const int*)d_in[5];
    float* out = (float*)d_out;

    const int total = in_sizes[1];               // B*N = 3,200,000
    const float inv_total = 1.0f / (float)total;

    if (ws_size < WS_NEED || total != RD_B * RD_N) {
        rd_zero_kernel<<<1, 1, 0, stream>>>(out);
        rd_loss_fallback<<<NXCD * FB_KPB, BDIM, 0, stream>>>(
            depth, xA, yA, xB, yB, ord, out, total, inv_total);
        return;
    }

    unsigned* counters = (unsigned*)((char*)d_ws + WS_COUNTERS_OFF);
    unsigned* records  = (unsigned*)((char*)d_ws + WS_RECORDS_OFF);
    float*    zpair    = (float*)((char*)d_ws + WS_ZPAIR_OFF);

    rd_init_kernel<<<(RD_B * NBANDS + BDIM - 1) / BDIM, BDIM, 0, stream>>>(out, counters);
    rd_bin_kernel<<<NXCD * IMGS_PER_XCD * P0_CHUNKS, BDIM, 0, stream>>>(   // 1568
        xA, yA, xB, yB, counters, records);
    rd_gather_kernel<<<NXCD * IMGS_PER_XCD * NBANDS, BDIM, 0, stream>>>(   // 4096
        depth, counters, records, zpair);
    rd_loss_from_z<<<NXCD * IMGS_PER_XCD * P0_CHUNKS, BDIM, 0, stream>>>(  // 1568
        zpair, ord, out, inv_total);
}